// Round 13
// baseline (16.769 us; speedup 1.0000x reference)
//
#include <hip/hip_runtime.h>

// NQ=8, NL=3, B=65536 — fused single kernel, 4-way split edition.
// Grid 256 blocks x 1024 thr. Threads (j = t&255, h = t>>8, h=0..3).
// Phase A: group h evolves 3 of 9 popcount-class columns (cols 2h..2h+2;
//   overlap columns written twice with identical values — benign).
// Phase B: restage full row C_j; the 81 quadratic products split 4 ways by
//   whole d-groups (max 22/group); single shared WHT buffer [4][7][81].
// Phase C: thread (j,h) evaluates sample j of the block, qubits 2h,2h+1,
//   coefficients via ds_read_b128 from padded rows g[8][92].
// vs R12: critical path ~halved again, 4 waves/SIMD (was 2).

#define ROW 92   // padded row: A@0(9) d1@12(16) d2@28(14) d3@44(12)
                 // d4@56(10) d5@68(8) d6@76(6) d7@84(4) d8@88(2)

template <int CTRL>
__device__ __forceinline__ float dppf(float x) {
    return __int_as_float(
        __builtin_amdgcn_mov_dpp(__float_as_int(x), CTRL, 0xF, 0xF, true));
}
template <int PAT>
__device__ __forceinline__ float swzp(float x) {
    return __int_as_float(__builtin_amdgcn_ds_swizzle(__float_as_int(x), PAT));
}
template <int B>
__device__ __forceinline__ float lane_xor(float x) {
    if constexpr (B == 0) return dppf<0xB1>(x);        // quad_perm xor1
    else if constexpr (B == 1) return dppf<0x4E>(x);   // quad_perm xor2
    else if constexpr (B == 2) return swzp<0x101F>(x); // ds_swizzle xor4
    else if constexpr (B == 3) return dppf<0x128>(x);  // row_ror:8 == xor8
    else if constexpr (B == 4) return swzp<0x401F>(x); // ds_swizzle xor16
    else return __shfl_xor(x, 32, 64);                 // xor32
}

// Fused RY(wire0) x RY(wire1) on j bits 7,6 — one LDS round, 3 columns.
__device__ __forceinline__ void gate_lds2_3(float2 Cv[3], float2 (*xch)[256],
                                            float2 cs0, float2 cs1,
                                            int j, int M0) {
    __syncthreads();
    #pragma unroll
    for (int m = 0; m < 3; ++m) xch[M0 + m][j] = Cv[m];
    __syncthreads();
    const float s0 = (j & 128) ? cs0.y : -cs0.y;
    const float s1 = (j & 64)  ? cs1.y : -cs1.y;
    const float a00 = cs0.x * cs1.x, a01 = cs0.x * s1;
    const float a10 = s0 * cs1.x,    a11 = s0 * s1;
    #pragma unroll
    for (int m = 0; m < 3; ++m) {
        const float2 p01 = xch[M0 + m][j ^ 64];
        const float2 p10 = xch[M0 + m][j ^ 128];
        const float2 p11 = xch[M0 + m][j ^ 192];
        Cv[m].x = a00 * Cv[m].x + a01 * p01.x + a10 * p10.x + a11 * p11.x;
        Cv[m].y = a00 * Cv[m].y + a01 * p01.y + a10 * p10.y + a11 * p11.y;
    }
}

template <int B>
__device__ __forceinline__ void gate_wave3(float2 Cv[3], float2 cs, int j) {
    const float sg = ((j >> B) & 1) ? cs.y : -cs.y;
    #pragma unroll
    for (int m = 0; m < 3; ++m) {
        const float pr = lane_xor<B>(Cv[m].x);
        const float pi = lane_xor<B>(Cv[m].y);
        Cv[m].x = cs.x * Cv[m].x + sg * pr;
        Cv[m].y = cs.x * Cv[m].y + sg * pi;
    }
}

template <int N>
__device__ __forceinline__ void wht_chunk(float (&v)[N], float* buf,
                                          int lane, int wvg, int row, int base) {
    #define WHT_LVL(B)                                                   \
    {                                                                    \
        const float sgn = ((lane >> (B)) & 1) ? -1.f : 1.f;              \
        _Pragma("unroll")                                                \
        for (int i = 0; i < N; ++i) {                                    \
            const float p = lane_xor<B>(v[i]);                           \
            v[i] = fmaf(sgn, v[i], p);                                   \
        }                                                                \
    }
    WHT_LVL(0) WHT_LVL(1) WHT_LVL(2) WHT_LVL(3) WHT_LVL(4) WHT_LVL(5)
    #undef WHT_LVL
    if (row >= 0) {
        #pragma unroll
        for (int i = 0; i < N; ++i) buf[(wvg * 7 + row) * 81 + base + i] = v[i];
    }
}

template <int D, int N>
__device__ __forceinline__ void fill_pairs(const float2 (&C9)[9], float (&c)[N],
                                           int off) {
    #pragma unroll
    for (int k = 0; k + D <= 8; ++k) {
        const float2 hi = C9[k + D], lo = C9[k];
        c[off + 2 * k]     = 2.f * (hi.x * lo.x + hi.y * lo.y);
        c[off + 2 * k + 1] = 2.f * (hi.y * lo.x - hi.x * lo.y);
    }
}

// ---- phase C helpers (single sample, static indices)
__device__ __forceinline__ void prep(float z1v, float z2v, float& u, float& w8,
                                     float Tr[9], float Ti[9]) {
    const float u1 = sqrtf(fmaxf(0.f, 1.f - z1v * z1v));   // cos a1
    const float q1 = 0.5f * (1.f + u1);                     // cos^2(a1/2)
    const float s1 = copysignf(sqrtf(fmaxf(0.f, 0.5f * (1.f - u1))), z1v);
    const float tn = s1 * rsqrtf(q1);                       // tan(a1/2)
    const float u2 = sqrtf(fmaxf(0.f, 1.f - z2v * z2v));    // cos a2
    const float tr = tn * u2, ti = tn * z2v;                // t = tn e^{i a2}
    u = tn * tn;
    w8 = q1 * q1; w8 *= w8; w8 *= w8;                       // q1^8
    Tr[1] = tr; Ti[1] = ti;
    #pragma unroll
    for (int d = 2; d <= 8; ++d) {
        Tr[d] = Tr[d - 1] * tr - Ti[d - 1] * ti;
        Ti[d] = Tr[d - 1] * ti + Ti[d - 1] * tr;
    }
}

__device__ __forceinline__ float apoly1(const float* gp, float u) {
    const float4 c0 = ((const float4*)gp)[0];
    const float4 c1 = ((const float4*)gp)[1];
    const float4 c2 = ((const float4*)gp)[2];
    const float a[9] = {c0.x, c0.y, c0.z, c0.w, c1.x, c1.y, c1.z, c1.w, c2.x};
    float r = a[8];
    #pragma unroll
    for (int m = 7; m >= 0; --m) r = fmaf(r, u, a[m]);
    return r;
}

template <int NP>   // NP (re,im) pairs, ascending k; returns (br, bi)
__device__ __forceinline__ float2 bpoly1(const float* gp, float u) {
    constexpr int NF4 = (2 * NP + 3) / 4;
    float4 c[NF4];
    const float4* p = (const float4*)gp;
    #pragma unroll
    for (int i = 0; i < NF4; ++i) c[i] = p[i];
    float br = 0.f, bi = 0.f;
    #pragma unroll
    for (int k = NP - 1; k >= 0; --k) {           // static indices only
        const float re = (k & 1) ? c[k >> 1].z : c[k >> 1].x;
        const float im = (k & 1) ? c[k >> 1].w : c[k >> 1].y;
        br = fmaf(br, u, re);
        bi = fmaf(bi, u, im);
    }
    return make_float2(br, bi);
}

__global__ __launch_bounds__(1024, 4)
void qsim_fused(const float* __restrict__ w, const float* __restrict__ z1,
                const float* __restrict__ z2, float* __restrict__ out,
                int nsamp) {
    __shared__ float2 xch[9][256];              // 18 KB gate/WHT buffer
    __shared__ float2 s_cs[3][8];
    __shared__ __align__(16) float g[8 * ROW];  // padded coeff rows

    const int t = threadIdx.x;
    const int j = t & 255;           // basis index AND sample slot
    const int h = t >> 8;            // group 0..3
    const int M0 = 2 * h;            // first owned column / qubit
    const int lane = t & 63, wvg = (t >> 6) & 3;   // wave within group

    // ---- hoist only the z LOADS (latency hides under phase A); prep later
    const int s = blockIdx.x * 256 + j;
    const bool ev = (s < nsamp);
    const float z1v = ev ? z1[s] : 0.f;
    const float z2v = ev ? z2[s] : 0.f;

    if (t < 24) {
        int l = t >> 3, q = t & 7;
        float a = 0.5f * w[l * 15 + q];
        s_cs[l][q] = make_float2(__cosf(a), __sinf(a));
    }
    __syncthreads();

    // ---- phase A: evolve 3 owned columns; groups cover all 9 (overlaps dup)
    float2 Cv[3];
    #pragma unroll
    for (int m = 0; m < 3; ++m)
        Cv[m] = make_float2((__popc(j) == M0 + m) ? 1.f : 0.f, 0.f);

    for (int l = 0; l < 3; ++l) {
        gate_lds2_3(Cv, xch, s_cs[l][0], s_cs[l][1], j, M0);  // bits 7,6
        gate_wave3<5>(Cv, s_cs[l][2], j);
        gate_wave3<4>(Cv, s_cs[l][3], j);
        gate_wave3<3>(Cv, s_cs[l][4], j);
        gate_wave3<2>(Cv, s_cs[l][5], j);
        gate_wave3<1>(Cv, s_cs[l][6], j);
        gate_wave3<0>(Cv, s_cs[l][7], j);
        if (l < 2) {                              // RZZ diag (last one cancels)
            float ang = 0.f;
            #pragma unroll
            for (int i = 0; i < 7; ++i) {
                float zz = (((j >> (7 - i)) ^ (j >> (6 - i))) & 1) ? -1.f : 1.f;
                ang = fmaf(w[l * 15 + 8 + i], zz, ang);
            }
            float s2, c2;
            __sincosf(0.5f * ang, &s2, &c2);
            #pragma unroll
            for (int m = 0; m < 3; ++m) {
                const float nr = Cv[m].x * c2 + Cv[m].y * s2;
                const float ni = Cv[m].y * c2 - Cv[m].x * s2;
                Cv[m].x = nr; Cv[m].y = ni;
            }
        }
    }

    // ---- restage: every thread gets the full row C_j
    __syncthreads();
    #pragma unroll
    for (int m = 0; m < 3; ++m) xch[M0 + m][j] = Cv[m];
    __syncthreads();
    float2 C9[9];
    #pragma unroll
    for (int m = 0; m < 9; ++m) C9[m] = xch[m][j];
    __syncthreads();

    // ---- phase B: group h WHTs its d-groups (disjoint columns, one buffer)
    float* buf = (float*)xch;        // [wvg 0..3][row 0..6][i 0..80]
    const int row = (lane == 0) ? 0 : (lane == 1) ? 1 : (lane == 2) ? 2 :
                    (lane == 4) ? 3 : (lane == 8) ? 4 : (lane == 16) ? 5 :
                    (lane == 32) ? 6 : -1;
    if (h == 0) {                    // diag (9) + d3 (12) = 21
        {   float c[9];
            #pragma unroll
            for (int m = 0; m < 9; ++m)
                c[m] = C9[m].x * C9[m].x + C9[m].y * C9[m].y;
            wht_chunk(c, buf, lane, wvg, row, 0);
        }
        { float c[12]; fill_pairs<3>(C9, c, 0); wht_chunk(c, buf, lane, wvg, row, 39); }
    } else if (h == 1) {             // d1 (16) + d8 (2) = 18
        { float c[16]; fill_pairs<1>(C9, c, 0); wht_chunk(c, buf, lane, wvg, row, 9);  }
        { float c[2];  fill_pairs<8>(C9, c, 0); wht_chunk(c, buf, lane, wvg, row, 79); }
    } else if (h == 2) {             // d2 (14) + d6 (6) = 20
        { float c[14]; fill_pairs<2>(C9, c, 0); wht_chunk(c, buf, lane, wvg, row, 25); }
        { float c[6];  fill_pairs<6>(C9, c, 0); wht_chunk(c, buf, lane, wvg, row, 69); }
    } else {                         // d4 (10) + d5 (8) + d7 (4) = 22
        { float c[10]; fill_pairs<4>(C9, c, 0); wht_chunk(c, buf, lane, wvg, row, 51); }
        { float c[8];  fill_pairs<5>(C9, c, 0); wht_chunk(c, buf, lane, wvg, row, 61); }
        { float c[4];  fill_pairs<7>(C9, c, 0); wht_chunk(c, buf, lane, wvg, row, 75); }
    }
    __syncthreads();
    // cross-wave combine into padded rows; qubit q <-> idx bit b = 7-q
    if (t < 648) {
        const int o = t;
        const int q = o / 81, i = o - 81 * q;
        const int b = 7 - q;
        float r;
        if (b < 6) {
            const int rw = b + 1;
            r = buf[(0 * 7 + rw) * 81 + i] + buf[(1 * 7 + rw) * 81 + i] +
                buf[(2 * 7 + rw) * 81 + i] + buf[(3 * 7 + rw) * 81 + i];
        } else if (b == 6) {
            r = buf[(0 * 7) * 81 + i] - buf[(1 * 7) * 81 + i] +
                buf[(2 * 7) * 81 + i] - buf[(3 * 7) * 81 + i];
        } else {
            r = buf[(0 * 7) * 81 + i] + buf[(1 * 7) * 81 + i] -
                buf[(2 * 7) * 81 + i] - buf[(3 * 7) * 81 + i];
        }
        // compact index -> padded offset (16B-aligned d-groups)
        const int off = i + ((i < 9) ? 0 : (i < 39) ? 3 : (i < 61) ? 5 :
                             (i < 75) ? 7 : 9);
        g[q * ROW + off] = r;
    }
    __syncthreads();

    // ---- phase C: thread (j,h) evaluates sample s, qubits 2h, 2h+1
    if (!ev) return;

    float u, w8;
    float Tr[9], Ti[9];
    prep(z1v, z2v, u, w8, Tr, Ti);

    float o2[2];
    #pragma unroll
    for (int k = 0; k < 2; ++k) {
        const float* gq = g + (M0 + k) * ROW;
        float r = apoly1(gq, u);
        #define DTERM(D, NP, OFF)                                        \
        {                                                                \
            const float2 b = bpoly1<NP>(gq + OFF, u);                    \
            r = fmaf(Tr[D], b.x, r);                                     \
            r = fmaf(-Ti[D], b.y, r);                                    \
        }
        DTERM(1, 8, 12) DTERM(2, 7, 28) DTERM(3, 6, 44) DTERM(4, 5, 56)
        DTERM(5, 4, 68) DTERM(6, 3, 76) DTERM(7, 2, 84) DTERM(8, 1, 88)
        #undef DTERM
        o2[k] = w8 * r;
    }

    float2* op = (float2*)(out + (size_t)s * 8 + M0);
    *op = make_float2(o2[0], o2[1]);
}

extern "C" void kernel_launch(void* const* d_in, const int* in_sizes, int n_in,
                              void* d_out, int out_size, void* d_ws,
                              size_t ws_size, hipStream_t stream) {
    const float* w  = (const float*)d_in[0];   // (3, 15) f32
    const float* z1 = (const float*)d_in[1];   // (B,)   f32
    const float* z2 = (const float*)d_in[2];   // (B,)   f32
    float* out = (float*)d_out;                // (B, 8) f32

    const int n = in_sizes[1];
    qsim_fused<<<(n + 255) / 256, 1024, 0, stream>>>(w, z1, z2, out, n);
}

// Round 14
// 16.273 us; speedup vs baseline: 1.0304x; 1.0304x over previous
//
#include <hip/hip_runtime.h>

// NQ=8, NL=3, B=65536 — fused single kernel. R12 base + coeff-amortized eval.
// Grid 256 blocks x 512 thr. Threads (j = t&255, h = t>>8).
// Phase A: thread (j,h) evolves 5 of 9 popcount-class columns (col 4 dup).
// Phase B: restage full row C_j; group h WHTs half of the 81 quadratic
//   products; cross-wave combine writes PADDED rows g[8][92] (16B groups).
// Phase C (NEW): thread t owns qubit q = t&7 and samples 4g..4g+3 (g = t>>3).
//   92 coeff floats loaded ONCE (23 ds_read_b128) and reused for 4 samples:
//   eval LDS 736 -> 184 wave-instrs/CU. prep() is 8x redundant (+0.25 us
//   VALU) — 10:1 favorable vs the LDS-pipe saving.

#define ROW 92   // padded row: A@0(9) d1@12(16) d2@28(14) d3@44(12)
                 // d4@56(10) d5@68(8) d6@76(6) d7@84(4) d8@88(2)

template <int CTRL>
__device__ __forceinline__ float dppf(float x) {
    return __int_as_float(
        __builtin_amdgcn_mov_dpp(__float_as_int(x), CTRL, 0xF, 0xF, true));
}
template <int PAT>
__device__ __forceinline__ float swzp(float x) {
    return __int_as_float(__builtin_amdgcn_ds_swizzle(__float_as_int(x), PAT));
}
template <int B>
__device__ __forceinline__ float lane_xor(float x) {
    if constexpr (B == 0) return dppf<0xB1>(x);        // quad_perm xor1
    else if constexpr (B == 1) return dppf<0x4E>(x);   // quad_perm xor2
    else if constexpr (B == 2) return swzp<0x101F>(x); // ds_swizzle xor4
    else if constexpr (B == 3) return dppf<0x128>(x);  // row_ror:8 == xor8
    else if constexpr (B == 4) return swzp<0x401F>(x); // ds_swizzle xor16
    else return __shfl_xor(x, 32, 64);                 // xor32
}

// Fused RY(wire0) x RY(wire1) on j bits 7,6 — one LDS round, 5 columns.
__device__ __forceinline__ void gate_lds2_5(float2 Cv[5], float2 (*xch)[256],
                                            float2 cs0, float2 cs1,
                                            int j, int M0) {
    __syncthreads();
    #pragma unroll
    for (int m = 0; m < 5; ++m) xch[M0 + m][j] = Cv[m];
    __syncthreads();
    const float s0 = (j & 128) ? cs0.y : -cs0.y;
    const float s1 = (j & 64)  ? cs1.y : -cs1.y;
    const float a00 = cs0.x * cs1.x, a01 = cs0.x * s1;
    const float a10 = s0 * cs1.x,    a11 = s0 * s1;
    #pragma unroll
    for (int m = 0; m < 5; ++m) {
        const float2 p01 = xch[M0 + m][j ^ 64];
        const float2 p10 = xch[M0 + m][j ^ 128];
        const float2 p11 = xch[M0 + m][j ^ 192];
        Cv[m].x = a00 * Cv[m].x + a01 * p01.x + a10 * p10.x + a11 * p11.x;
        Cv[m].y = a00 * Cv[m].y + a01 * p01.y + a10 * p10.y + a11 * p11.y;
    }
}

template <int B>
__device__ __forceinline__ void gate_wave5(float2 Cv[5], float2 cs, int j) {
    const float sg = ((j >> B) & 1) ? cs.y : -cs.y;
    #pragma unroll
    for (int m = 0; m < 5; ++m) {
        const float pr = lane_xor<B>(Cv[m].x);
        const float pi = lane_xor<B>(Cv[m].y);
        Cv[m].x = cs.x * Cv[m].x + sg * pr;
        Cv[m].y = cs.x * Cv[m].y + sg * pi;
    }
}

template <int N>
__device__ __forceinline__ void wht_chunk(float (&v)[N], float* buf,
                                          int lane, int wvg, int row, int base) {
    #define WHT_LVL(B)                                                   \
    {                                                                    \
        const float sgn = ((lane >> (B)) & 1) ? -1.f : 1.f;              \
        _Pragma("unroll")                                                \
        for (int i = 0; i < N; ++i) {                                    \
            const float p = lane_xor<B>(v[i]);                           \
            v[i] = fmaf(sgn, v[i], p);                                   \
        }                                                                \
    }
    WHT_LVL(0) WHT_LVL(1) WHT_LVL(2) WHT_LVL(3) WHT_LVL(4) WHT_LVL(5)
    #undef WHT_LVL
    if (row >= 0) {
        #pragma unroll
        for (int i = 0; i < N; ++i) buf[(wvg * 7 + row) * 81 + base + i] = v[i];
    }
}

template <int D, int N>
__device__ __forceinline__ void fill_pairs(const float2 (&C9)[9], float (&c)[N],
                                           int off) {
    #pragma unroll
    for (int k = 0; k + D <= 8; ++k) {
        const float2 hi = C9[k + D], lo = C9[k];
        c[off + 2 * k]     = 2.f * (hi.x * lo.x + hi.y * lo.y);
        c[off + 2 * k + 1] = 2.f * (hi.y * lo.x - hi.x * lo.y);
    }
}

// ---- per-sample prep (static indices)
__device__ __forceinline__ void prep(float z1v, float z2v, float& u, float& w8,
                                     float Tr[9], float Ti[9]) {
    const float u1 = sqrtf(fmaxf(0.f, 1.f - z1v * z1v));   // cos a1
    const float q1 = 0.5f * (1.f + u1);                     // cos^2(a1/2)
    const float s1 = copysignf(sqrtf(fmaxf(0.f, 0.5f * (1.f - u1))), z1v);
    const float tn = s1 * rsqrtf(q1);                       // tan(a1/2)
    const float u2 = sqrtf(fmaxf(0.f, 1.f - z2v * z2v));    // cos a2
    const float tr = tn * u2, ti = tn * z2v;                // t = tn e^{i a2}
    u = tn * tn;
    w8 = q1 * q1; w8 *= w8; w8 *= w8;                       // q1^8
    Tr[1] = tr; Ti[1] = ti;
    #pragma unroll
    for (int d = 2; d <= 8; ++d) {
        Tr[d] = Tr[d - 1] * tr - Ti[d - 1] * ti;
        Ti[d] = Tr[d - 1] * ti + Ti[d - 1] * tr;
    }
}

__global__ __launch_bounds__(512, 2)
void qsim_fused(const float* __restrict__ w, const float* __restrict__ z1,
                const float* __restrict__ z2, float* __restrict__ out,
                int nsamp) {
    __shared__ float2 xch[9][256];              // 18 KB gate/WHT buffer
    __shared__ float2 s_cs[3][8];
    __shared__ __align__(16) float g[8 * ROW];  // padded coeff rows

    const int t = threadIdx.x;
    const int j = t & 255;           // basis index
    const int h = t >> 8;            // column/component group
    const int M0 = h * 4;
    const int lane = t & 63, wvg = (t >> 6) & 3;

    // ---- phase C inputs hoisted: thread t -> qubit q = t&7, samples 4g..4g+3
    const int gidx = t >> 3;                       // 0..63
    const int sbase = blockIdx.x * 256 + gidx * 4; // first sample
    const bool ev4 = (sbase + 3 < nsamp);
    float4 z1v4 = make_float4(0.f, 0.f, 0.f, 0.f);
    float4 z2v4 = z1v4;
    if (ev4) {
        z1v4 = *(const float4*)(z1 + sbase);
        z2v4 = *(const float4*)(z2 + sbase);
    }

    if (t < 24) {
        int l = t >> 3, q = t & 7;
        float a = 0.5f * w[l * 15 + q];
        s_cs[l][q] = make_float2(__cosf(a), __sinf(a));
    }
    __syncthreads();

    // ---- phase A: evolve 5 owned columns; pair (j,0/1) covers all 9
    float2 Cv[5];
    #pragma unroll
    for (int m = 0; m < 5; ++m)
        Cv[m] = make_float2((__popc(j) == M0 + m) ? 1.f : 0.f, 0.f);

    for (int l = 0; l < 3; ++l) {
        gate_lds2_5(Cv, xch, s_cs[l][0], s_cs[l][1], j, M0);  // bits 7,6
        gate_wave5<5>(Cv, s_cs[l][2], j);
        gate_wave5<4>(Cv, s_cs[l][3], j);
        gate_wave5<3>(Cv, s_cs[l][4], j);
        gate_wave5<2>(Cv, s_cs[l][5], j);
        gate_wave5<1>(Cv, s_cs[l][6], j);
        gate_wave5<0>(Cv, s_cs[l][7], j);
        if (l < 2) {                              // RZZ diag (last one cancels)
            float ang = 0.f;
            #pragma unroll
            for (int i = 0; i < 7; ++i) {
                float zz = (((j >> (7 - i)) ^ (j >> (6 - i))) & 1) ? -1.f : 1.f;
                ang = fmaf(w[l * 15 + 8 + i], zz, ang);
            }
            float s2, c2;
            __sincosf(0.5f * ang, &s2, &c2);
            #pragma unroll
            for (int m = 0; m < 5; ++m) {
                const float nr = Cv[m].x * c2 + Cv[m].y * s2;
                const float ni = Cv[m].y * c2 - Cv[m].x * s2;
                Cv[m].x = nr; Cv[m].y = ni;
            }
        }
    }

    // ---- restage: every thread gets the full row C_j
    __syncthreads();
    #pragma unroll
    for (int m = 0; m < 5; ++m) xch[M0 + m][j] = Cv[m];
    __syncthreads();
    float2 C9[9];
    #pragma unroll
    for (int m = 0; m < 9; ++m) C9[m] = xch[m][j];
    __syncthreads();

    // ---- phase B: group h WHTs its component subset
    float* buf = (float*)xch + h * (28 * 81);
    const int row = (lane == 0) ? 0 : (lane == 1) ? 1 : (lane == 2) ? 2 :
                    (lane == 4) ? 3 : (lane == 8) ? 4 : (lane == 16) ? 5 :
                    (lane == 32) ? 6 : -1;
    if (h == 0) {                    // components 0..38: diag, d=1, d=2
        {   float c[9];
            #pragma unroll
            for (int m = 0; m < 9; ++m)
                c[m] = C9[m].x * C9[m].x + C9[m].y * C9[m].y;
            wht_chunk(c, buf, lane, wvg, row, 0);
        }
        { float c[16]; fill_pairs<1>(C9, c, 0); wht_chunk(c, buf, lane, wvg, row, 9);  }
        { float c[14]; fill_pairs<2>(C9, c, 0); wht_chunk(c, buf, lane, wvg, row, 25); }
    } else {                         // components 39..80: d=3..8
        { float c[12]; fill_pairs<3>(C9, c, 0); wht_chunk(c, buf, lane, wvg, row, 39); }
        { float c[10]; fill_pairs<4>(C9, c, 0); wht_chunk(c, buf, lane, wvg, row, 51); }
        { float c[8];  fill_pairs<5>(C9, c, 0); wht_chunk(c, buf, lane, wvg, row, 61); }
        {   float c[12];
            fill_pairs<6>(C9, c, 0);
            fill_pairs<7>(C9, c, 6);
            fill_pairs<8>(C9, c, 10);
            wht_chunk(c, buf, lane, wvg, row, 69);
        }
    }
    __syncthreads();
    // cross-wave combine into padded rows; qubit q <-> idx bit b = 7-q
    for (int o = t; o < 648; o += 512) {
        const int q = o / 81, i = o - 81 * q;
        const int b = 7 - q;
        const float* gb = (const float*)xch + ((i < 39) ? 0 : 28 * 81);
        float r;
        if (b < 6) {
            const int rw = b + 1;
            r = gb[(0 * 7 + rw) * 81 + i] + gb[(1 * 7 + rw) * 81 + i] +
                gb[(2 * 7 + rw) * 81 + i] + gb[(3 * 7 + rw) * 81 + i];
        } else if (b == 6) {
            r = gb[(0 * 7) * 81 + i] - gb[(1 * 7) * 81 + i] +
                gb[(2 * 7) * 81 + i] - gb[(3 * 7) * 81 + i];
        } else {
            r = gb[(0 * 7) * 81 + i] + gb[(1 * 7) * 81 + i] -
                gb[(2 * 7) * 81 + i] - gb[(3 * 7) * 81 + i];
        }
        // compact index -> padded offset (16B-aligned d-groups)
        const int off = i + ((i < 9) ? 0 : (i < 39) ? 3 : (i < 61) ? 5 :
                             (i < 75) ? 7 : 9);
        g[q * ROW + off] = r;
    }
    __syncthreads();

    // ---- phase C: thread t = (qubit q, 4 samples); coeffs loaded once
    const int q = t & 7;
    const float* gq = g + q * ROW;

    float a[ROW];                     // 23 ds_read_b128, fully unrolled
    #pragma unroll
    for (int i = 0; i < 23; ++i) {
        const float4 c = ((const float4*)gq)[i];
        a[4 * i + 0] = c.x; a[4 * i + 1] = c.y;
        a[4 * i + 2] = c.z; a[4 * i + 3] = c.w;
    }

    const float z1a[4] = {z1v4.x, z1v4.y, z1v4.z, z1v4.w};
    const float z2a[4] = {z2v4.x, z2v4.y, z2v4.z, z2v4.w};
    float o4[4];

    #pragma unroll
    for (int i = 0; i < 4; ++i) {
        float u, w8;
        float Tr[9], Ti[9];
        prep(z1a[i], z2a[i], u, w8, Tr, Ti);

        float r = a[8];
        #pragma unroll
        for (int m = 7; m >= 0; --m) r = fmaf(r, u, a[m]);

        #define DTERM(D, NP, OFF)                                        \
        {                                                                \
            float br = a[OFF + 2 * (NP - 1)];                            \
            float bi = a[OFF + 2 * (NP - 1) + 1];                        \
            _Pragma("unroll")                                            \
            for (int k = NP - 2; k >= 0; --k) {                          \
                br = fmaf(br, u, a[OFF + 2 * k]);                        \
                bi = fmaf(bi, u, a[OFF + 2 * k + 1]);                    \
            }                                                            \
            r = fmaf(Tr[D], br, r);                                      \
            r = fmaf(-Ti[D], bi, r);                                     \
        }
        DTERM(1, 8, 12) DTERM(2, 7, 28) DTERM(3, 6, 44) DTERM(4, 5, 56)
        DTERM(5, 4, 68) DTERM(6, 3, 76) DTERM(7, 2, 84) DTERM(8, 1, 88)
        #undef DTERM
        o4[i] = w8 * r;
    }

    if (ev4) {
        #pragma unroll
        for (int i = 0; i < 4; ++i)
            out[(size_t)(sbase + i) * 8 + q] = o4[i];
    } else {
        #pragma unroll
        for (int i = 0; i < 4; ++i)
            if (sbase + i < nsamp) out[(size_t)(sbase + i) * 8 + q] = o4[i];
    }
}

extern "C" void kernel_launch(void* const* d_in, const int* in_sizes, int n_in,
                              void* d_out, int out_size, void* d_ws,
                              size_t ws_size, hipStream_t stream) {
    const float* w  = (const float*)d_in[0];   // (3, 15) f32
    const float* z1 = (const float*)d_in[1];   // (B,)   f32
    const float* z2 = (const float*)d_in[2];   // (B,)   f32
    float* out = (float*)d_out;                // (B, 8) f32

    const int n = in_sizes[1];
    qsim_fused<<<(n + 255) / 256, 512, 0, stream>>>(w, z1, z2, out, n);
}